// Round 1
// 224.379 us; speedup vs baseline: 1.0087x; 1.0087x over previous
//
#include <hip/hip_runtime.h>

// RIDE 4-way self-distillation KL loss, N x C (C=7), fp32. Scalar output.
//
// R6 post-mortem: ride_main 82.5us, OccupancyPercent ~19, VALUBusy ~18,
// MfmaUtil 0, HBM 16% of peak -> pure latency bound. Two causes:
//  (1) grid=512 blocks on 256 CUs = 2 blocks/CU resident even though
//      launch_bounds(256,5) + 28672B LDS allow 5. Only 2 waves/SIMD to
//      hide load latency.
//  (2) VGPR_Count=48 < q[28]+staged[28] minimum -> the scheduler sank the
//      "prefetch" loads down to their ds_write consumers again (R5 convoy:
//      issue load -> vmcnt(0) -> stall, every step).
//
// R7: same algorithm, two changes.
//  - CPW=1: grid 2048 blocks -> 5 blocks/CU resident (LDS-limited),
//    20 waves/CU (~62% occupancy cap vs 25%).
//  - sched_barrier(0) fences pin the step order:
//        ds_write staged -> issue next step's 7 loads -> compute.
//    This keeps the 28 staged VGPRs live across the compute phase so each
//    step's loads fly under the *previous* step's compute (true depth-1
//    pipeline). Budget: q[28] + staged[28] + temps ~ 80 VGPR < 102 cap.
//
// Unchanged from R6 (all verified): wave-private single-buffer LDS
// (7168 B/wave, zero __syncthreads, same-wave DS-pipe ordering makes the
// single buffer correct), conflict-free stride-7-word b32 ds_reads
// (2 lanes/bank = free), lane-contiguous dwordx4 global loads, per-wave
// partials + tiny reduce kernel (no same-address atomic tail).

struct RideConsts {
    float invT[7];
    float scale;   // mean(T^2) / (3*N)
};

template <int CPW>   // chunks (256 rows) per wave
__global__ __launch_bounds__(256, 5) void ride_main(
    const float* __restrict__ x1, const float* __restrict__ x2,
    const float* __restrict__ x3, const float* __restrict__ x4,
    float* __restrict__ partials, RideConsts cst)
{
    // 4 waves/block, each with a private 1792-float region. 28672 B total.
    __shared__ __align__(16) float lds[4][1792];

    const int t = threadIdx.x;
    const int w = t >> 6;
    const int L = t & 63;
    float* myLds = lds[w];

    const float* xs[4] = {x1, x2, x3, x4};
    const int waveId = blockIdx.x * 4 + w;

    // float4 base for (chunk c, array a): (f4*)xs[a] + (waveId*CPW + c)*448 + L
    const long long cbase = (long long)waveId * CPW * 448 + L;

    float4 v0, v1, v2, v3, v4, v5, v6;

    // Prologue: load step 0 (chunk 0, array 0). Lane-contiguous dwordx4.
    {
        const float4* gp = (const float4*)xs[0] + cbase;
        v0 = gp[0];   v1 = gp[64];  v2 = gp[128]; v3 = gp[192];
        v4 = gp[256]; v5 = gp[320]; v6 = gp[384];
    }

    float q[28], qlogq[4];
    float cost = 0.0f;

#pragma unroll
    for (int c = 0; c < CPW; ++c) {
#pragma unroll
        for (int a = 0; a < 4; ++a) {
            // 1) Commit staged step to private LDS (vmcnt wait here is for
            //    loads issued one full compute-step ago). ds_write_b128.
            {
                float4* dst = (float4*)myLds;
                dst[0 * 64 + L] = v0; dst[1 * 64 + L] = v1;
                dst[2 * 64 + L] = v2; dst[3 * 64 + L] = v3;
                dst[4 * 64 + L] = v4; dst[5 * 64 + L] = v5;
                dst[6 * 64 + L] = v6;
            }
            // Fence: commits stay above the next-step loads.
            __builtin_amdgcn_sched_barrier(0);

            // 2) Issue next step's loads (static condition; none on the very
            //    last step). They fly during the compute below.
            if (c * 4 + a + 1 < CPW * 4) {
                const int na = (a + 1) & 3;
                const int nc = (a == 3) ? c + 1 : c;
                const float4* gp = (const float4*)xs[na] + (cbase + nc * 448);
                v0 = gp[0];   v1 = gp[64];  v2 = gp[128]; v3 = gp[192];
                v4 = gp[256]; v5 = gp[320]; v6 = gp[384];
            }
            // Fence: loads are ISSUED here, before compute; scheduler may not
            // sink them to their ds_write consumers (the R5/R6 convoy).
            __builtin_amdgcn_sched_barrier(0);

            // 3) Compute this step: lane L owns rows L+64*rr, at word offset
            //    7L + 448*rr (stride-7 b32 reads: 2 lanes/bank, free).
            if (a == 0) {
#pragma unroll
                for (int rr = 0; rr < 4; ++rr) {
                    const float* r = &myLds[7 * L + 448 * rr];
                    float z[7], m = -1e30f;
#pragma unroll
                    for (int cc = 0; cc < 7; ++cc) {
                        z[cc] = r[cc] * cst.invT[cc];
                        m = fmaxf(m, z[cc]);
                    }
                    float S = 0.0f;
#pragma unroll
                    for (int cc = 0; cc < 7; ++cc) {
                        float e = __expf(z[cc] - m);
                        q[7 * rr + cc] = e; S += e;
                    }
                    const float invS = 1.0f / S, logS = __logf(S);
                    float sq = 0.0f;
#pragma unroll
                    for (int cc = 0; cc < 7; ++cc) {
                        float qq = q[7 * rr + cc] * invS;
                        q[7 * rr + cc] = qq;
                        sq += qq * (z[cc] - m - logS);
                    }
                    qlogq[rr] = sq;
                }
            } else {
#pragma unroll
                for (int rr = 0; rr < 4; ++rr) {
                    const float* r = &myLds[7 * L + 448 * rr];
                    float z[7], m = -1e30f;
#pragma unroll
                    for (int cc = 0; cc < 7; ++cc) {
                        z[cc] = r[cc] * cst.invT[cc];
                        m = fmaxf(m, z[cc]);
                    }
                    float S = 0.0f, dot = 0.0f;
#pragma unroll
                    for (int cc = 0; cc < 7; ++cc) {
                        S   += __expf(z[cc] - m);
                        dot += q[7 * rr + cc] * z[cc];
                    }
                    cost += qlogq[rr] - dot + m + __logf(S);
                }
            }
        }
    }

    cost *= (1.0f / 7.0f);   // mean over C
    cost *= cst.scale;

    // Wave-level reduce; one plain store per wave. No atomics, no barriers.
#pragma unroll
    for (int off = 32; off > 0; off >>= 1)
        cost += __shfl_down(cost, off, 64);
    if (L == 0) partials[waveId] = cost;
}

__global__ __launch_bounds__(256) void ride_reduce(
    const float* __restrict__ p, float* __restrict__ out, int n4)
{
    // n4 = number of float4s (n % 1024 == 0 guaranteed by launch config).
    const float4* p4 = (const float4*)p;
    float s = 0.0f;
    for (int i = threadIdx.x; i < n4; i += 256) {
        float4 v = p4[i];
        s += (v.x + v.y) + (v.z + v.w);
    }
#pragma unroll
    for (int off = 32; off > 0; off >>= 1)
        s += __shfl_down(s, off, 64);
    __shared__ float red[4];
    if ((threadIdx.x & 63) == 0) red[threadIdx.x >> 6] = s;
    __syncthreads();
    if (threadIdx.x == 0) out[0] = red[0] + red[1] + red[2] + red[3];
}

extern "C" void kernel_launch(void* const* d_in, const int* in_sizes, int n_in,
                              void* d_out, int out_size, void* d_ws, size_t ws_size,
                              hipStream_t stream)
{
    const float* x1 = (const float*)d_in[0];
    const float* x2 = (const float*)d_in[1];
    const float* x3 = (const float*)d_in[2];
    const float* x4 = (const float*)d_in[3];
    // d_in[4] = targets: dead input, never read.

    const int N = in_sizes[0] / 7;   // 2097152

    RideConsts cst;
    {
        const double cls[7] = {705, 717, 281, 4772, 1982, 1290, 2524};
        double sum = 0.0;
        for (int c = 0; c < 7; ++c) sum += cls[c];
        double w[7], wmax = 0.0;
        for (int c = 0; c < 7; ++c) {
            const double p = cls[c] / sum;
            w[c] = 7.0 * p * 0.015 + 1.0 - 0.015;
            if (w[c] > wmax) wmax = w[c];
        }
        double mT2 = 0.0;
        for (int c = 0; c < 7; ++c) {
            const float T = (float)(1.5 * (w[c] / wmax));
            cst.invT[c] = 1.0f / T;
            mT2 += (double)T * (double)T;
        }
        mT2 /= 7.0;
        cst.scale = (float)(mT2 / (3.0 * (double)N));
    }

    // N = 2097152 rows = 8192 chunks of 256 rows.
    // CPW=1: 8192 waves = 2048 blocks -> 8 blocks/CU scheduled, 5 resident
    // (LDS-limited), 20 waves/CU.
    constexpr int CPW = 1;
    const int nWaves = (N / 256) / CPW;     // 8192
    const int grid   = nWaves / 4;          // 2048

    float* partials = (float*)d_ws;         // 8192 floats = 32 KB scratch

    ride_main<CPW><<<grid, 256, 0, stream>>>(x1, x2, x3, x4, partials, cst);
    ride_reduce<<<1, 256, 0, stream>>>(partials, (float*)d_out, nWaves / 4);
}